// Round 2
// baseline (576.275 us; speedup 1.0000x reference)
//
#include <hip/hip_runtime.h>
#include <cstdint>
#include <cstddef>

// Fused transformer block: out = LN(FFN(LN(attn(x)+x)) + LN(attn(x)+x))
// Z=64, N=2048, D=64, DFF=32, causal, single head.
// ws layout: Qb bf16 | Kb bf16 | Vt bf16 [Z][D][N] | attn fp32  (~84 MB)

#define ZB   64
#define NCTX 2048
#define DH   64
#define DFF  32
#define NEGC (-1e9f)
#define SM_SCALE 0.125f

typedef float f32x4 __attribute__((ext_vector_type(4)));
typedef __bf16 bf16x8 __attribute__((ext_vector_type(8)));

#define MFMA(a, b, c) __builtin_amdgcn_mfma_f32_16x16x32_bf16((a), (b), (c), 0, 0, 0)

static __device__ __forceinline__ float red16_max(float v) {
  v = fmaxf(v, __shfl_xor(v, 1));
  v = fmaxf(v, __shfl_xor(v, 2));
  v = fmaxf(v, __shfl_xor(v, 4));
  v = fmaxf(v, __shfl_xor(v, 8));
  return v;
}
static __device__ __forceinline__ float red16_sum(float v) {
  v += __shfl_xor(v, 1);
  v += __shfl_xor(v, 2);
  v += __shfl_xor(v, 4);
  v += __shfl_xor(v, 8);
  return v;
}

// ---------------------------------------------------------------------------
// Kernel 1: QKV projection. grid = Z*N/64 blocks, 192 threads (3 waves).
// Wave w computes matrix w (Q/K/V) for 64 rows; weights live in 64 VGPRs/lane.
// V is written transposed [b][d][n] via an LDS transpose tile.
// ---------------------------------------------------------------------------
__global__ __launch_bounds__(192) void proj_kernel(
    const float* __restrict__ x, const float* __restrict__ wq,
    const float* __restrict__ wk, const float* __restrict__ wv,
    __bf16* __restrict__ Qb, __bf16* __restrict__ Kb, __bf16* __restrict__ Vt)
{
  const int b  = blockIdx.x >> 5;           // N/64 = 32 tiles per batch
  const int n0 = (blockIdx.x & 31) << 6;
  const int w  = threadIdx.x >> 6;
  const int l  = threadIdx.x & 63;

  __shared__ __bf16 vtile[64][66];          // padded: conflict-free transpose read

  const float* wsel = (w == 0) ? wq : (w == 1) ? wk : wv;
  float wreg[64];
  #pragma unroll
  for (int d = 0; d < 64; ++d) wreg[d] = wsel[d * 64 + l];  // column l of weight

  const size_t rb0 = ((size_t)b * NCTX + n0) * DH;
  for (int n = 0; n < 64; ++n) {
    const float* xr = x + rb0 + (size_t)n * DH;   // wave-uniform address
    float acc = 0.f;
    #pragma unroll
    for (int d = 0; d < 64; ++d) acc += xr[d] * wreg[d];
    if (w == 0)      Qb[rb0 + n * DH + l] = (__bf16)acc;
    else if (w == 1) Kb[rb0 + n * DH + l] = (__bf16)acc;
    else             vtile[n][l] = (__bf16)acc;
  }
  if (w == 2) {
    asm volatile("s_waitcnt lgkmcnt(0)" ::: "memory");
    __builtin_amdgcn_sched_barrier(0);
    #pragma unroll 8
    for (int d = 0; d < 64; ++d)
      Vt[((size_t)b * 64 + d) * NCTX + n0 + l] = vtile[l][d];
  }
}

// ---------------------------------------------------------------------------
// Kernel 2: causal flash attention. grid = Z*N/64 blocks, 256 threads.
// Each wave independently owns 16 q-rows; kv tiles of 32; bf16 MFMA 16x16x32.
// P round-trips through a per-wave LDS buffer (C-layout -> A-frag layout).
// ---------------------------------------------------------------------------
__global__ __launch_bounds__(256) void attn_kernel(
    const __bf16* __restrict__ Qb, const __bf16* __restrict__ Kb,
    const __bf16* __restrict__ Vt, const float* __restrict__ kpm,
    float* __restrict__ attn)
{
  const int b  = blockIdx.x >> 5;
  const int q0 = (blockIdx.x & 31) << 6;
  const int w  = threadIdx.x >> 6;
  const int l  = threadIdx.x & 63;
  const int lo = l & 15, hi = l >> 4;
  const int qw = q0 + w * 16;

  __shared__ __bf16 plds[4][16][40];        // per-wave P buffer, padded stride

  const size_t qoff = ((size_t)b * NCTX + qw + lo) * DH + hi * 8;
  const bf16x8 qa0 = *(const bf16x8*)(Qb + qoff);        // A-frag d 0..31
  const bf16x8 qa1 = *(const bf16x8*)(Qb + qoff + 32);   // A-frag d 32..63

  f32x4 acc[4] = {{0,0,0,0},{0,0,0,0},{0,0,0,0},{0,0,0,0}};
  float m[4], ls[4];
  #pragma unroll
  for (int r = 0; r < 4; ++r) { m[r] = -__builtin_inff(); ls[r] = 0.f; }

  const int kv_end = qw + 16;               // causal upper bound for this wave
  for (int kv0 = 0; kv0 < kv_end; kv0 += 32) {
    // K B-frags: B[k=d][col=kv] = K[kv][d], contiguous 8 d's per lane
    const __bf16* kp = Kb + ((size_t)b * NCTX + kv0 + lo) * DH + hi * 8;
    const bf16x8 kb00 = *(const bf16x8*)(kp);
    const bf16x8 kb01 = *(const bf16x8*)(kp + 32);
    const bf16x8 kb10 = *(const bf16x8*)(kp + 16 * DH);
    const bf16x8 kb11 = *(const bf16x8*)(kp + 16 * DH + 32);
    const f32x4 z = {0, 0, 0, 0};
    f32x4 s0 = MFMA(qa0, kb00, z); s0 = MFMA(qa1, kb01, s0);   // kv cols 0..15
    f32x4 s1 = MFMA(qa0, kb10, z); s1 = MFMA(qa1, kb11, s1);   // kv cols 16..31

    const int j0 = kv0 + lo, j1 = j0 + 16;
    const float kp0 = kpm[b * NCTX + j0];
    const float kp1 = kpm[b * NCTX + j1];
    float p0[4], p1[4], tm[4];
    #pragma unroll
    for (int r = 0; r < 4; ++r) {
      const int i = qw + hi * 4 + r;        // this acc element's q row
      const float v0 = (s0[r] + kp0 + (j0 > i ? NEGC : 0.f)) * SM_SCALE;
      const float v1 = (s1[r] + kp1 + (j1 > i ? NEGC : 0.f)) * SM_SCALE;
      p0[r] = v0; p1[r] = v1; tm[r] = fmaxf(v0, v1);
    }
    #pragma unroll
    for (int r = 0; r < 4; ++r) tm[r] = red16_max(tm[r]);
    float rs[4];
    #pragma unroll
    for (int r = 0; r < 4; ++r) {
      const float mn = fmaxf(m[r], tm[r]);
      const float sc = __expf(m[r] - mn);   // m=-inf first iter -> sc=0, fine
      m[r] = mn;
      p0[r] = __expf(p0[r] - mn);
      p1[r] = __expf(p1[r] - mn);
      rs[r] = p0[r] + p1[r];
      ls[r] *= sc;
      #pragma unroll
      for (int dt = 0; dt < 4; ++dt) acc[dt][r] *= sc;
    }
    #pragma unroll
    for (int r = 0; r < 4; ++r) ls[r] += red16_sum(rs[r]);

    // P: C-layout -> LDS -> A-frag layout (wave-internal, rule-18 fences)
    asm volatile("s_waitcnt lgkmcnt(0)" ::: "memory");
    __builtin_amdgcn_sched_barrier(0);
    #pragma unroll
    for (int r = 0; r < 4; ++r) {
      plds[w][hi * 4 + r][lo]      = (__bf16)p0[r];
      plds[w][hi * 4 + r][lo + 16] = (__bf16)p1[r];
    }
    asm volatile("s_waitcnt lgkmcnt(0)" ::: "memory");
    __builtin_amdgcn_sched_barrier(0);
    const bf16x8 pa = *(const bf16x8*)(&plds[w][lo][hi * 8]);

    // V B-frags from transposed layout: contiguous 8 kv's per lane
    const __bf16* vp = Vt + ((size_t)b * 64 + lo) * NCTX + kv0 + hi * 8;
    #pragma unroll
    for (int dt = 0; dt < 4; ++dt) {
      const bf16x8 vb = *(const bf16x8*)(vp + (size_t)dt * 16 * NCTX);
      acc[dt] = MFMA(pa, vb, acc[dt]);
    }
  }

  #pragma unroll
  for (int r = 0; r < 4; ++r) {
    const float inv = 1.f / ls[r];
    const size_t ob = ((size_t)b * NCTX + qw + hi * 4 + r) * DH + lo;
    #pragma unroll
    for (int dt = 0; dt < 4; ++dt) attn[ob + dt * 16] = acc[dt][r] * inv;
  }
}

// ---------------------------------------------------------------------------
// Kernel 3: y=LN(attn+x); h=relu(y@w1); ff=h@w2; out=LN(ff+y).
// grid = Z*N/64, 256 threads; wave = one 16-row tile; FFN via MFMA.
// ---------------------------------------------------------------------------
__global__ __launch_bounds__(256) void ffn_kernel(
    const float* __restrict__ attn, const float* __restrict__ x,
    const float* __restrict__ w1, const float* __restrict__ w2,
    float* __restrict__ out)
{
  const int w  = threadIdx.x >> 6;
  const int l  = threadIdx.x & 63;
  const int lo = l & 15, hi = l >> 4;
  const int base = blockIdx.x * 64 + w * 16;   // absolute first row of tile

  __shared__ float  yf[4][16][68];   // fp32 y (residual precision)
  __shared__ __bf16 yb[4][16][72];   // bf16 y (MFMA A operand)
  __shared__ __bf16 hb[4][16][40];   // bf16 h

  // Weight B-frags in registers (fp32 global -> bf16)
  bf16x8 w1b[2][2], w2b[4];
  #pragma unroll
  for (int ct = 0; ct < 2; ++ct)
    #pragma unroll
    for (int h = 0; h < 2; ++h) {
      bf16x8 t;
      #pragma unroll
      for (int i = 0; i < 8; ++i)
        t[i] = (__bf16)w1[(h * 32 + hi * 8 + i) * DFF + ct * 16 + lo];
      w1b[ct][h] = t;
    }
  #pragma unroll
  for (int dt = 0; dt < 4; ++dt) {
    bf16x8 t;
    #pragma unroll
    for (int i = 0; i < 8; ++i)
      t[i] = (__bf16)w2[(hi * 8 + i) * DH + dt * 16 + lo];
    w2b[dt] = t;
  }

  // Stage 1: residual + LN, lane = d
  for (int r16 = 0; r16 < 16; ++r16) {
    const size_t row = (size_t)(base + r16) * DH + l;
    const float t = attn[row] + x[row];
    float s = t, s2 = t * t;
    #pragma unroll
    for (int mk = 1; mk < 64; mk <<= 1) {
      s += __shfl_xor(s, mk);
      s2 += __shfl_xor(s2, mk);
    }
    const float mu  = s * (1.f / 64.f);
    const float var = s2 * (1.f / 64.f) - mu * mu;
    const float y   = (t - mu) * rsqrtf(var + 1e-5f);
    yf[w][r16][l] = y;
    yb[w][r16][l] = (__bf16)y;
  }
  asm volatile("s_waitcnt lgkmcnt(0)" ::: "memory");
  __builtin_amdgcn_sched_barrier(0);

  // Stage 2: h = relu(y @ w1)
  const bf16x8 ya0 = *(const bf16x8*)(&yb[w][lo][hi * 8]);
  const bf16x8 ya1 = *(const bf16x8*)(&yb[w][lo][32 + hi * 8]);
  const f32x4 z = {0, 0, 0, 0};
  f32x4 h0 = MFMA(ya0, w1b[0][0], z); h0 = MFMA(ya1, w1b[0][1], h0);
  f32x4 h1 = MFMA(ya0, w1b[1][0], z); h1 = MFMA(ya1, w1b[1][1], h1);
  #pragma unroll
  for (int r = 0; r < 4; ++r) {
    h0[r] = fmaxf(h0[r], 0.f);
    h1[r] = fmaxf(h1[r], 0.f);
    hb[w][hi * 4 + r][lo]      = (__bf16)h0[r];
    hb[w][hi * 4 + r][lo + 16] = (__bf16)h1[r];
  }
  asm volatile("s_waitcnt lgkmcnt(0)" ::: "memory");
  __builtin_amdgcn_sched_barrier(0);

  // Stage 3: ff = h @ w2, residual, LN, store
  const bf16x8 ha = *(const bf16x8*)(&hb[w][lo][hi * 8]);
  f32x4 ff[4];
  #pragma unroll
  for (int dt = 0; dt < 4; ++dt) ff[dt] = MFMA(ha, w2b[dt], z);

  float val[4][4];
  #pragma unroll
  for (int dt = 0; dt < 4; ++dt)
    #pragma unroll
    for (int r = 0; r < 4; ++r)
      val[dt][r] = ff[dt][r] + yf[w][hi * 4 + r][dt * 16 + lo];

  #pragma unroll
  for (int r = 0; r < 4; ++r) {
    float s = 0.f, s2 = 0.f;
    #pragma unroll
    for (int dt = 0; dt < 4; ++dt) { s += val[dt][r]; s2 += val[dt][r] * val[dt][r]; }
    s  = red16_sum(s);
    s2 = red16_sum(s2);
    const float mu   = s * (1.f / 64.f);
    const float var  = s2 * (1.f / 64.f) - mu * mu;
    const float rstd = rsqrtf(var + 1e-5f);
    const size_t ob = (size_t)(base + hi * 4 + r) * DH + lo;
    #pragma unroll
    for (int dt = 0; dt < 4; ++dt) out[ob + dt * 16] = (val[dt][r] - mu) * rstd;
  }
}

// ---------------------------------------------------------------------------
extern "C" void kernel_launch(void* const* d_in, const int* in_sizes, int n_in,
                              void* d_out, int out_size, void* d_ws, size_t ws_size,
                              hipStream_t stream)
{
  const float* x   = (const float*)d_in[0];
  const float* wq  = (const float*)d_in[1];
  const float* wk  = (const float*)d_in[2];
  const float* wv  = (const float*)d_in[3];
  const float* w1  = (const float*)d_in[4];
  const float* w2  = (const float*)d_in[5];
  const float* kpm = (const float*)d_in[6];
  // d_in[7] = causal_mask: handled structurally (triu(k=1) == -1e9 additive)
  float* out = (float*)d_out;

  char* ws = (char*)d_ws;
  const size_t nelem = (size_t)ZB * NCTX * DH;     // 8388608
  __bf16* Qb = (__bf16*)(ws);
  __bf16* Kb = (__bf16*)(ws + nelem * 2);
  __bf16* Vt = (__bf16*)(ws + nelem * 4);          // [Z][D][N]
  float*  at = (float*)(ws + nelem * 6);           // fp32 attn out

  const int nblk = ZB * NCTX / 64;                 // 2048
  proj_kernel<<<nblk, 192, 0, stream>>>(x, wq, wk, wv, Qb, Kb, Vt);
  attn_kernel<<<nblk, 256, 0, stream>>>(Qb, Kb, Vt, kpm, at);
  ffn_kernel <<<nblk, 256, 0, stream>>>(at, x, w1, w2, out);
}

// Round 3
// 265.604 us; speedup vs baseline: 2.1697x; 2.1697x over previous
//
#include <hip/hip_runtime.h>
#include <cstdint>
#include <cstddef>

// Fused transformer block: out = LN(FFN(LN(attn(x)+x)) + LN(attn(x)+x))
// Z=64, N=2048, D=64, DFF=32, causal, single head.
// ws layout: Qb bf16 | Kb bf16 | Vt bf16 [Z][D][N] | attn fp32  (~84 MB)

#define ZB   64
#define NCTX 2048
#define DH   64
#define DFF  32
#define NEGC (-1e9f)
#define SM_SCALE 0.125f
// base-2 softmax: score*SM_SCALE*log2(e); mask -1e9 pre-scale -> NEGS2 in log2 domain
#define SC2   0.18033688011112042f
#define NEGS2 (-1.8033688e8f)

typedef float f32x4  __attribute__((ext_vector_type(4)));
typedef float f32x16 __attribute__((ext_vector_type(16)));
typedef __bf16 bf16x8 __attribute__((ext_vector_type(8)));
typedef unsigned int u32x4 __attribute__((ext_vector_type(4)));

#define MFMA(a, b, c)   __builtin_amdgcn_mfma_f32_16x16x32_bf16((a), (b), (c), 0, 0, 0)
#define MFMA32(a, b, c) __builtin_amdgcn_mfma_f32_32x32x16_bf16((a), (b), (c), 0, 0, 0)

static __device__ __forceinline__ float red16_sum(float v) {
  v += __shfl_xor(v, 1);
  v += __shfl_xor(v, 2);
  v += __shfl_xor(v, 4);
  v += __shfl_xor(v, 8);
  return v;
}
static __device__ __forceinline__ unsigned cvtpk_bf16(float a, float b) {
  unsigned r;
  asm("v_cvt_pk_bf16_f32 %0, %1, %2" : "=v"(r) : "v"(a), "v"(b));
  return r;
}
static __device__ __forceinline__ void plswap32(unsigned &a, unsigned &b) {
  asm volatile("v_permlane32_swap_b32 %0, %1" : "+v"(a), "+v"(b));
}
static __device__ __forceinline__ float exp2a(float x) {
  float r;
  asm("v_exp_f32 %0, %1" : "=v"(r) : "v"(x));
  return r;
}

// ---------------------------------------------------------------------------
// Kernel 1: QKV projection. grid = Z*N/64 blocks, 192 threads (3 waves).
// Wave w computes matrix w (Q/K/V) for 64 rows; weights live in 64 VGPRs/lane.
// V is written transposed [b][d][n] via an LDS transpose tile.
// ---------------------------------------------------------------------------
__global__ __launch_bounds__(192) void proj_kernel(
    const float* __restrict__ x, const float* __restrict__ wq,
    const float* __restrict__ wk, const float* __restrict__ wv,
    __bf16* __restrict__ Qb, __bf16* __restrict__ Kb, __bf16* __restrict__ Vt)
{
  const int b  = blockIdx.x >> 5;           // N/64 = 32 tiles per batch
  const int n0 = (blockIdx.x & 31) << 6;
  const int w  = threadIdx.x >> 6;
  const int l  = threadIdx.x & 63;

  __shared__ __bf16 vtile[64][66];          // padded: conflict-free transpose read

  const float* wsel = (w == 0) ? wq : (w == 1) ? wk : wv;
  float wreg[64];
  #pragma unroll
  for (int d = 0; d < 64; ++d) wreg[d] = wsel[d * 64 + l];  // column l of weight

  const size_t rb0 = ((size_t)b * NCTX + n0) * DH;
  for (int n = 0; n < 64; ++n) {
    const float* xr = x + rb0 + (size_t)n * DH;   // wave-uniform address
    float acc = 0.f;
    #pragma unroll
    for (int d = 0; d < 64; ++d) acc += xr[d] * wreg[d];
    if (w == 0)      Qb[rb0 + n * DH + l] = (__bf16)acc;
    else if (w == 1) Kb[rb0 + n * DH + l] = (__bf16)acc;
    else             vtile[n][l] = (__bf16)acc;
  }
  if (w == 2) {
    asm volatile("s_waitcnt lgkmcnt(0)" ::: "memory");
    __builtin_amdgcn_sched_barrier(0);
    #pragma unroll 8
    for (int d = 0; d < 64; ++d)
      Vt[((size_t)b * 64 + d) * NCTX + n0 + l] = vtile[l][d];
  }
}

// ---------------------------------------------------------------------------
// Kernel 2: causal flash attention, swapped-QK 32x32 in-register softmax.
// grid = Z*32 blocks x 128 threads (2 waves). Wave 0 -> q-tile tp, wave 1 ->
// q-tile 63-tp (balanced: every block = 65 kv-tile iterations). No LDS.
// S^T = mfma32(K,Q): lane owns q-row (l&31); 16 kv vals/lane + partner(l^32).
// P -> PV B-frags via v_cvt_pk_bf16_f32 + v_permlane32_swap_b32 (T12).
// O^T = mfma32(V^T, P^T) accumulated in 32 regs; base-2 online softmax with
// defer-max (T13, THR=11 in log2 domain).
// ---------------------------------------------------------------------------
__global__ __launch_bounds__(128) void attn_kernel(
    const __bf16* __restrict__ Qb, const __bf16* __restrict__ Kb,
    const __bf16* __restrict__ Vt, const float* __restrict__ kpm,
    float* __restrict__ attn)
{
  const int bid = (blockIdx.x & 7) * 256 + (blockIdx.x >> 3);  // XCD chunking
  const int b   = bid >> 5;
  const int tp  = bid & 31;
  const int wv  = threadIdx.x >> 6;
  const int l   = threadIdx.x & 63;
  const int q5  = l & 31;
  const int hi  = l >> 5;
  const int t   = wv ? (63 - tp) : tp;
  const int qw  = t << 5;

  // Q fragments: lane supplies Q[qw+q5][16c + 8hi + i]  (B-operand, col = q)
  const __bf16* qp = Qb + ((size_t)(b * NCTX + qw + q5)) * DH + hi * 8;
  bf16x8 qf[4];
  #pragma unroll
  for (int c = 0; c < 4; ++c) qf[c] = *(const bf16x8*)(qp + 16 * c);

  f32x16 acc[2];
  #pragma unroll
  for (int r = 0; r < 16; ++r) { acc[0][r] = 0.f; acc[1][r] = 0.f; }
  float m_run = -1e30f, ls = 0.f;

  const float*  kpb   = kpm + b * NCTX;
  const __bf16* kbase = Kb + ((size_t)b * NCTX + q5) * DH + hi * 8;
  const __bf16* vbase = Vt + ((size_t)(b * DH + q5)) * NCTX + hi * 8;

  for (int kv0 = 0; kv0 <= qw; kv0 += 32) {
    const bool diag = (kv0 == qw);          // wave-uniform

    // S^T = K_tile . Q^T : 4 MFMAs over D=64
    const __bf16* kp = kbase + (size_t)kv0 * DH;
    f32x16 s;
    #pragma unroll
    for (int r = 0; r < 16; ++r) s[r] = 0.f;
    #pragma unroll
    for (int c = 0; c < 4; ++c) {
      const bf16x8 kf = *(const bf16x8*)(kp + (size_t)16 * c);
      s = MFMA32(kf, qf[c], s);
    }

    // key-padding-mask values for this lane's 16 kv slots (reg r -> kv rm(r))
    f32x4 kb[4];
    #pragma unroll
    for (int g = 0; g < 4; ++g)
      kb[g] = *(const f32x4*)(kpb + kv0 + 4 * hi + 8 * g);

    float p[16];
    #pragma unroll
    for (int r = 0; r < 16; ++r) {
      float tv = (s[r] + kb[r >> 2][r & 3]) * SC2;
      if (diag) {
        const int rm = (r & 3) + 8 * (r >> 2) + 4 * hi;   // kv offset in tile
        tv = (rm > q5) ? tv + NEGS2 : tv;                 // causal: j > i
      }
      p[r] = tv;
    }

    // row max: in-lane tree + partner exchange
    float m0 = fmaxf(fmaxf(p[0], p[1]),  fmaxf(p[2], p[3]));
    float m1 = fmaxf(fmaxf(p[4], p[5]),  fmaxf(p[6], p[7]));
    float m2 = fmaxf(fmaxf(p[8], p[9]),  fmaxf(p[10], p[11]));
    float m3 = fmaxf(fmaxf(p[12], p[13]), fmaxf(p[14], p[15]));
    float mx = fmaxf(fmaxf(m0, m1), fmaxf(m2, m3));
    mx = fmaxf(mx, __shfl_xor(mx, 32));

    if (!__all(mx <= m_run + 11.0f)) {      // defer-max (T13)
      const float mn = fmaxf(m_run, mx);
      const float sc = exp2a(m_run - mn);   // first iter: exp2(-1e30)=0
      m_run = mn;
      ls *= sc;
      #pragma unroll
      for (int r = 0; r < 16; ++r) { acc[0][r] *= sc; acc[1][r] *= sc; }
    }

    #pragma unroll
    for (int r = 0; r < 16; ++r) p[r] = exp2a(p[r] - m_run);
    float t0 = (p[0] + p[1])  + (p[2] + p[3]);
    float t1 = (p[4] + p[5])  + (p[6] + p[7]);
    float t2 = (p[8] + p[9])  + (p[10] + p[11]);
    float t3 = (p[12] + p[13]) + (p[14] + p[15]);
    float rs = (t0 + t1) + (t2 + t3);
    rs += __shfl_xor(rs, 32);
    ls += rs;

    // P^T -> bf16 B-frags (kv 0..15 and 16..31) via cvt_pk + permlane32_swap
    unsigned a0 = cvtpk_bf16(p[0], p[1]),   b0 = cvtpk_bf16(p[4], p[5]);
    unsigned a1 = cvtpk_bf16(p[2], p[3]),   b1 = cvtpk_bf16(p[6], p[7]);
    plswap32(a0, b0); plswap32(a1, b1);
    unsigned c0 = cvtpk_bf16(p[8], p[9]),   d0 = cvtpk_bf16(p[12], p[13]);
    unsigned c1 = cvtpk_bf16(p[10], p[11]), d1 = cvtpk_bf16(p[14], p[15]);
    plswap32(c0, d0); plswap32(c1, d1);
    u32x4 u0 = {a0, a1, b0, b1};
    u32x4 u1 = {c0, c1, d0, d1};
    const bf16x8 pf0 = __builtin_bit_cast(bf16x8, u0);
    const bf16x8 pf1 = __builtin_bit_cast(bf16x8, u1);

    // O^T += V^T . P^T : A-frag = Vt rows (d), 2 d-blocks x 2 kv-halves
    const __bf16* vp = vbase + kv0;
    acc[0] = MFMA32(*(const bf16x8*)(vp),                        pf0, acc[0]);
    acc[0] = MFMA32(*(const bf16x8*)(vp + 16),                   pf1, acc[0]);
    acc[1] = MFMA32(*(const bf16x8*)(vp + (size_t)32 * NCTX),      pf0, acc[1]);
    acc[1] = MFMA32(*(const bf16x8*)(vp + (size_t)32 * NCTX + 16), pf1, acc[1]);
  }

  // epilogue: O^T reg r of block db -> out[qw+q5][32db + (r&3)+8(r>>2)+4hi]
  const float invl = 1.f / ls;
  float* op = attn + ((size_t)(b * NCTX + qw + q5)) * DH + 4 * hi;
  #pragma unroll
  for (int db = 0; db < 2; ++db)
    #pragma unroll
    for (int g = 0; g < 4; ++g) {
      f32x4 st;
      #pragma unroll
      for (int j = 0; j < 4; ++j) st[j] = acc[db][4 * g + j] * invl;
      *(f32x4*)(op + 32 * db + 8 * g) = st;
    }
}

// ---------------------------------------------------------------------------
// Kernel 3: y=LN(attn+x); h=relu(y@w1); ff=h@w2; out=LN(ff+y).
// grid = Z*N/64, 256 threads; wave = one 16-row tile; FFN via MFMA.
// ---------------------------------------------------------------------------
__global__ __launch_bounds__(256) void ffn_kernel(
    const float* __restrict__ attn, const float* __restrict__ x,
    const float* __restrict__ w1, const float* __restrict__ w2,
    float* __restrict__ out)
{
  const int w  = threadIdx.x >> 6;
  const int l  = threadIdx.x & 63;
  const int lo = l & 15, hi = l >> 4;
  const int base = blockIdx.x * 64 + w * 16;   // absolute first row of tile

  __shared__ float  yf[4][16][68];   // fp32 y (residual precision)
  __shared__ __bf16 yb[4][16][72];   // bf16 y (MFMA A operand)
  __shared__ __bf16 hb[4][16][40];   // bf16 h

  // Weight B-frags in registers (fp32 global -> bf16)
  bf16x8 w1b[2][2], w2b[4];
  #pragma unroll
  for (int ct = 0; ct < 2; ++ct)
    #pragma unroll
    for (int h = 0; h < 2; ++h) {
      bf16x8 t;
      #pragma unroll
      for (int i = 0; i < 8; ++i)
        t[i] = (__bf16)w1[(h * 32 + hi * 8 + i) * DFF + ct * 16 + lo];
      w1b[ct][h] = t;
    }
  #pragma unroll
  for (int dt = 0; dt < 4; ++dt) {
    bf16x8 t;
    #pragma unroll
    for (int i = 0; i < 8; ++i)
      t[i] = (__bf16)w2[(hi * 8 + i) * DH + dt * 16 + lo];
    w2b[dt] = t;
  }

  // Stage 1: residual + LN, lane = d
  for (int r16 = 0; r16 < 16; ++r16) {
    const size_t row = (size_t)(base + r16) * DH + l;
    const float t = attn[row] + x[row];
    float s = t, s2 = t * t;
    #pragma unroll
    for (int mk = 1; mk < 64; mk <<= 1) {
      s += __shfl_xor(s, mk);
      s2 += __shfl_xor(s2, mk);
    }
    const float mu  = s * (1.f / 64.f);
    const float var = s2 * (1.f / 64.f) - mu * mu;
    const float y   = (t - mu) * rsqrtf(var + 1e-5f);
    yf[w][r16][l] = y;
    yb[w][r16][l] = (__bf16)y;
  }
  asm volatile("s_waitcnt lgkmcnt(0)" ::: "memory");
  __builtin_amdgcn_sched_barrier(0);

  // Stage 2: h = relu(y @ w1)
  const bf16x8 ya0 = *(const bf16x8*)(&yb[w][lo][hi * 8]);
  const bf16x8 ya1 = *(const bf16x8*)(&yb[w][lo][32 + hi * 8]);
  const f32x4 z = {0, 0, 0, 0};
  f32x4 h0 = MFMA(ya0, w1b[0][0], z); h0 = MFMA(ya1, w1b[0][1], h0);
  f32x4 h1 = MFMA(ya0, w1b[1][0], z); h1 = MFMA(ya1, w1b[1][1], h1);
  #pragma unroll
  for (int r = 0; r < 4; ++r) {
    h0[r] = fmaxf(h0[r], 0.f);
    h1[r] = fmaxf(h1[r], 0.f);
    hb[w][hi * 4 + r][lo]      = (__bf16)h0[r];
    hb[w][hi * 4 + r][lo + 16] = (__bf16)h1[r];
  }
  asm volatile("s_waitcnt lgkmcnt(0)" ::: "memory");
  __builtin_amdgcn_sched_barrier(0);

  // Stage 3: ff = h @ w2, residual, LN, store
  const bf16x8 ha = *(const bf16x8*)(&hb[w][lo][hi * 8]);
  f32x4 ff[4];
  #pragma unroll
  for (int dt = 0; dt < 4; ++dt) ff[dt] = MFMA(ha, w2b[dt], z);

  float val[4][4];
  #pragma unroll
  for (int dt = 0; dt < 4; ++dt)
    #pragma unroll
    for (int r = 0; r < 4; ++r)
      val[dt][r] = ff[dt][r] + yf[w][hi * 4 + r][dt * 16 + lo];

  #pragma unroll
  for (int r = 0; r < 4; ++r) {
    float s = 0.f, s2 = 0.f;
    #pragma unroll
    for (int dt = 0; dt < 4; ++dt) { s += val[dt][r]; s2 += val[dt][r] * val[dt][r]; }
    s  = red16_sum(s);
    s2 = red16_sum(s2);
    const float mu   = s * (1.f / 64.f);
    const float var  = s2 * (1.f / 64.f) - mu * mu;
    const float rstd = rsqrtf(var + 1e-5f);
    const size_t ob = (size_t)(base + hi * 4 + r) * DH + lo;
    #pragma unroll
    for (int dt = 0; dt < 4; ++dt) out[ob + dt * 16] = (val[dt][r] - mu) * rstd;
  }
}

// ---------------------------------------------------------------------------
extern "C" void kernel_launch(void* const* d_in, const int* in_sizes, int n_in,
                              void* d_out, int out_size, void* d_ws, size_t ws_size,
                              hipStream_t stream)
{
  const float* x   = (const float*)d_in[0];
  const float* wq  = (const float*)d_in[1];
  const float* wk  = (const float*)d_in[2];
  const float* wv  = (const float*)d_in[3];
  const float* w1  = (const float*)d_in[4];
  const float* w2  = (const float*)d_in[5];
  const float* kpm = (const float*)d_in[6];
  // d_in[7] = causal_mask: handled structurally (triu(k=1) == -1e9 additive)
  float* out = (float*)d_out;

  char* ws = (char*)d_ws;
  const size_t nelem = (size_t)ZB * NCTX * DH;     // 8388608
  __bf16* Qb = (__bf16*)(ws);
  __bf16* Kb = (__bf16*)(ws + nelem * 2);
  __bf16* Vt = (__bf16*)(ws + nelem * 4);          // [Z][D][N]
  float*  at = (float*)(ws + nelem * 6);           // fp32 attn out

  const int nblk = ZB * NCTX / 64;                 // 2048
  proj_kernel<<<nblk, 192, 0, stream>>>(x, wq, wk, wv, Qb, Kb, Vt);
  attn_kernel<<<ZB * 32, 128, 0, stream>>>(Qb, Kb, Vt, kpm, at);
  ffn_kernel <<<nblk, 256, 0, stream>>>(at, x, w1, w2, out);
}